// Round 1
// baseline (917.938 us; speedup 1.0000x reference)
//
#include <hip/hip_runtime.h>
#include <stdint.h>

#define N_T 25
#define HW2 16384          // 128*128
#define PB  409600         // N_T*HW2, flat per-batch size
#define NB  32
#define MTHRESH 8323072u   // 2^23 - 2^16  -> candidate prob 1/128
#define SLOT 4096

__device__ __forceinline__ uint32_t rotl32(uint32_t x, uint32_t r){ return (x<<r)|(x>>(32u-r)); }

// Exact Threefry-2x32 (20 rounds), matches jax._src.prng.threefry2x32
__device__ __forceinline__ void tf2x32(uint32_t k0,uint32_t k1,uint32_t x0,uint32_t x1,
                                       uint32_t& o0,uint32_t& o1){
  uint32_t k2 = k0 ^ k1 ^ 0x1BD11BDAu;
  x0 += k0; x1 += k1;
#define RND(r) { x0 += x1; x1 = rotl32(x1,(r)); x1 ^= x0; }
  RND(13) RND(15) RND(26) RND(6)
  x0 += k1; x1 += k2 + 1u;
  RND(17) RND(29) RND(16) RND(24)
  x0 += k2; x1 += k0 + 2u;
  RND(13) RND(15) RND(26) RND(6)
  x0 += k0; x1 += k1 + 3u;
  RND(17) RND(29) RND(16) RND(24)
  x0 += k1; x1 += k2 + 4u;
  RND(13) RND(15) RND(26) RND(6)
  x0 += k2; x1 += k0 + 5u;
#undef RND
  o0 = x0; o1 = x1;
}

__device__ __forceinline__ float softplus_f(float x){
  return fmaxf(x, 0.0f) + log1pf(expf(-fabsf(x)));
}

// Pass 1: compute pr bits for every (b, j); candidates (pr in top 1/128) read
// class_map + classification, apply hard-negative mining, append composite key
// (m desc, idx asc via ~idx) to the per-(sign,batch) list.
__global__ void k_scan(const float* __restrict__ output,
                       const float* __restrict__ class_map,
                       int* __restrict__ cnt,                      // 64 ints
                       unsigned long long* __restrict__ keys)      // 64*SLOT
{
  int b = blockIdx.y;
  // jax.random.split(key(42), 32), partitionable path: key_b = threefry((0,42),(0,b))
  uint32_t kb0, kb1;
  tf2x32(0u, 42u, 0u, (uint32_t)b, kb0, kb1);

  int j = blockIdx.x * blockDim.x + threadIdx.x;
  if (j >= PB) return;
  // partitionable random_bits(32): bits = o0 ^ o1 of threefry(key_b, (0, j))
  uint32_t o0, o1;
  tf2x32(kb0, kb1, 0u, (uint32_t)j, o0, o1);
  uint32_t m = (o0 ^ o1) >> 9;           // pr = m * 2^-23 exactly; order by m
  if (m < MTHRESH) return;

  float cmv = class_map[(size_t)b * PB + j];
  if (cmv == 0.0f) return;
  int t = j >> 14, s = j & (HW2 - 1);
  float cls = output[((size_t)b * 125 + t) * HW2 + s];
  float sp = softplus_f(-cmv * cls);
  if (sp < 0.03f) return;                 // mined out (easy example)

  int sign = (cmv > 0.0f) ? 0 : 1;
  int slot = sign * NB + b;
  int n = atomicAdd(&cnt[slot], 1);
  if (n < SLOT) {
    unsigned long long key =
        (((unsigned long long)m) << 19) | (unsigned long long)(j ^ 0x7FFFF);
    keys[(size_t)slot * SLOT + n] = key;
  }
}

// Pass 2: per (batch, sign) block: bitonic-sort candidates descending
// (= pr desc, idx asc), take top-128, compute class loss (+ smooth-L1 reg
// loss for positives), reduce, atomicAdd into the scalar output.
__global__ void k_select(const float* __restrict__ output,
                         const float* __restrict__ regmap,
                         const int* __restrict__ cnt,
                         const unsigned long long* __restrict__ keys,
                         float* __restrict__ out)
{
  __shared__ unsigned long long sk[SLOT];
  __shared__ float red[256];
  int b    = blockIdx.x;    // 0..31
  int sign = blockIdx.y;    // 0 = pos, 1 = neg
  int slot = sign * NB + b;
  int tid  = threadIdx.x;

  int n = cnt[slot]; if (n > SLOT) n = SLOT;
  for (int i = tid; i < SLOT; i += 256)
    sk[i] = (i < n) ? keys[(size_t)slot * SLOT + i] : 0ULL;
  __syncthreads();

  // bitonic sort, descending
  for (int k = 2; k <= SLOT; k <<= 1) {
    for (int jj = k >> 1; jj > 0; jj >>= 1) {
      for (int i = tid; i < SLOT; i += 256) {
        int ixj = i ^ jj;
        if (ixj > i) {
          unsigned long long a = sk[i], c = sk[ixj];
          bool desc = ((i & k) == 0);
          if (desc ? (a < c) : (a > c)) { sk[i] = c; sk[ixj] = a; }
        }
      }
      __syncthreads();
    }
  }

  int take = n < 128 ? n : 128;
  float acc = 0.0f;
  if (tid < take) {
    unsigned long long key = sk[tid];
    int j = (int)(key & 0x7FFFFULL) ^ 0x7FFFF;
    int t = j >> 14, s = j & (HW2 - 1);
    float cls = output[((size_t)b * 125 + t) * HW2 + s];
    if (sign == 0) {
      acc = softplus_f(-cls);            // cm = +1
      #pragma unroll
      for (int c = 0; c < 4; ++c) {      // reg channels t, t+25, t+50, t+75
        float r = output[((size_t)b * 125 + 25 + c * 25 + t) * HW2 + s];
        float g = regmap[((size_t)b * 100 + c * 25 + t) * HW2 + s];
        float d = r - g;
        float ad = fabsf(d);
        acc += (ad < 1.0f) ? 0.5f * d * d : ad - 0.5f;
      }
    } else {
      acc = softplus_f(cls);             // cm = -1
    }
  }
  red[tid] = acc;
  __syncthreads();
  for (int st = 128; st > 0; st >>= 1) {
    if (tid < st) red[tid] += red[tid + st];
    __syncthreads();
  }
  if (tid == 0) atomicAdd(out, red[0]);
}

extern "C" void kernel_launch(void* const* d_in, const int* in_sizes, int n_in,
                              void* d_out, int out_size, void* d_ws, size_t ws_size,
                              hipStream_t stream) {
  const float* output    = (const float*)d_in[0];   // (32,125,128,128)
  const float* class_map = (const float*)d_in[1];   // (32,25,128,128)
  const float* regmap    = (const float*)d_in[2];   // (32,100,128,128)
  float* out = (float*)d_out;

  int* cnt = (int*)d_ws;                                           // 64 ints
  unsigned long long* keys = (unsigned long long*)((char*)d_ws + 256); // 64*SLOT u64

  hipMemsetAsync(d_ws, 0, 256, stream);
  hipMemsetAsync(d_out, 0, sizeof(float) * (size_t)out_size, stream);

  dim3 g1((PB + 255) / 256, NB);
  k_scan<<<g1, 256, 0, stream>>>(output, class_map, cnt, keys);

  dim3 g2(NB, 2);
  k_select<<<g2, 256, 0, stream>>>(output, regmap, cnt, keys, out);
}

// Round 2
// 490.326 us; speedup vs baseline: 1.8721x; 1.8721x over previous
//
#include <hip/hip_runtime.h>
#include <stdint.h>

#define HW2 16384          // 128*128
#define PB  409600         // 25*HW2, flat per-batch size
#define NB  32
#define MTHRESH 8323072u   // 2^23 - 2^16  -> candidate prob 1/128
#define NSEG 32            // sub-segments per (sign,batch) slot (atomic spreading)
#define SEGCAP 124         // keys per segment (mean ~33, 15 sigma headroom)
#define MAXK (NSEG*SEGCAP) // 3968

__device__ __forceinline__ uint32_t rotl32(uint32_t x, uint32_t r){ return (x<<r)|(x>>(32u-r)); }

// Exact Threefry-2x32 (20 rounds), matches jax._src.prng.threefry2x32
__device__ __forceinline__ void tf2x32(uint32_t k0,uint32_t k1,uint32_t x0,uint32_t x1,
                                       uint32_t& o0,uint32_t& o1){
  uint32_t k2 = k0 ^ k1 ^ 0x1BD11BDAu;
  x0 += k0; x1 += k1;
#define RND(r) { x0 += x1; x1 = rotl32(x1,(r)); x1 ^= x0; }
  RND(13) RND(15) RND(26) RND(6)
  x0 += k1; x1 += k2 + 1u;
  RND(17) RND(29) RND(16) RND(24)
  x0 += k2; x1 += k0 + 2u;
  RND(13) RND(15) RND(26) RND(6)
  x0 += k0; x1 += k1 + 3u;
  RND(17) RND(29) RND(16) RND(24)
  x0 += k1; x1 += k2 + 4u;
  RND(13) RND(15) RND(26) RND(6)
  x0 += k2; x1 += k0 + 5u;
#undef RND
  o0 = x0; o1 = x1;
}

__device__ __forceinline__ float softplus_f(float x){
  return fmaxf(x, 0.0f) + log1pf(expf(-fabsf(x)));
}

// Pass 1: pr bits for every (b,j); candidates (top 1/128 by pr) read
// class_map + classification, apply hard-negative mining, append composite
// key (m desc, idx asc via xor) to one of 32 sub-segments of the
// per-(sign,batch) list. Sub-segments spread the atomic counters across
// 2048 addresses (R1: 64 addrs in 4 lines serialized -> 381 us).
__global__ void k_scan(const float* __restrict__ output,
                       const float* __restrict__ class_map,
                       int* __restrict__ cnt,                      // 64*NSEG ints
                       unsigned long long* __restrict__ keys)      // 64*NSEG*SEGCAP
{
  int b = blockIdx.y;
  uint32_t kb0, kb1;                 // key_b = threefry((0,42),(0,b)) — uniform, scalarizes
  tf2x32(0u, 42u, 0u, (uint32_t)b, kb0, kb1);

  int j = blockIdx.x * 256 + threadIdx.x;      // PB = 1600*256 exactly
  uint32_t o0, o1;
  tf2x32(kb0, kb1, 0u, (uint32_t)j, o0, o1);
  uint32_t m = (o0 ^ o1) >> 9;                 // pr = m * 2^-23 exactly
  if (m < MTHRESH) return;

  // classification element for flat idx j is at the same per-batch offset j
  const float* cmb = class_map + (size_t)b * PB;
  const float* ob  = output    + (size_t)b * 125 * HW2;
  float cmv = cmb[j];                          // issue both loads concurrently
  float cls = ob[j];
  if (cmv == 0.0f) return;
  float sp = softplus_f(-cmv * cls);
  if (sp < 0.03f) return;                      // mined out (easy example)

  int sign = (cmv > 0.0f) ? 0 : 1;
  int slot = sign * NB + b;
  int seg  = blockIdx.x & (NSEG - 1);
  int c    = slot * NSEG + seg;
  int n = atomicAdd(&cnt[c], 1);
  if (n < SEGCAP) {
    keys[(size_t)c * SEGCAP + n] =
        (((unsigned long long)m) << 19) | (unsigned long long)(j ^ 0x7FFFF);
  }
}

// Pass 2: per (batch,sign) block: exact top-128 selection via 2-level 8-bit
// radix select on m (16 varying bits), tie-broken by idx on a tiny tie set,
// then gather losses and reduce. Replaces R1's 78-pass bitonic sort.
__global__ void k_select(const float* __restrict__ output,
                         const float* __restrict__ regmap,
                         const int* __restrict__ cnt,
                         const unsigned long long* __restrict__ keys,
                         float* __restrict__ out)
{
  __shared__ unsigned long long sk[MAXK];
  __shared__ int scnt[NSEG], sbase[NSEG];
  __shared__ int hist[256];
  __shared__ int sB1, sRem1, sB2, sRem2, sTieCnt, sN;
  __shared__ unsigned long long tie[64];
  __shared__ unsigned long long sKmin;
  __shared__ float red[256];

  int b    = blockIdx.x;    // 0..31
  int sign = blockIdx.y;    // 0 = pos, 1 = neg
  int slot = sign * NB + b;
  int tid  = threadIdx.x;

  if (tid < NSEG) {
    int c = cnt[slot * NSEG + tid];
    scnt[tid] = c > SEGCAP ? SEGCAP : c;
  }
  __syncthreads();
  if (tid == 0) {
    int s = 0;
    for (int i = 0; i < NSEG; ++i) { sbase[i] = s; s += scnt[i]; }
    sN = s;
  }
  __syncthreads();
  int n = sN;
  for (int u = tid; u < NSEG * SEGCAP; u += 256) {
    int seg = u / SEGCAP, i = u - seg * SEGCAP;
    if (i < scnt[seg])
      sk[sbase[seg] + i] = keys[(size_t)(slot * NSEG + seg) * SEGCAP + i];
  }
  __syncthreads();

  if (n > 128) {
    // level 1: m bits 15..8 (key bits 34..27)
    hist[tid] = 0; __syncthreads();
    for (int i = tid; i < n; i += 256)
      atomicAdd(&hist[(int)((sk[i] >> 27) & 0xFF)], 1);
    __syncthreads();
    if (tid == 0) {
      int c = 0, b1 = 255;
      for (;; --b1) { c += hist[b1]; if (c >= 128) break; }
      sB1 = b1; sRem1 = 128 - (c - hist[b1]);
    }
    __syncthreads();
    int B1 = sB1, rem1 = sRem1;
    // level 2: m bits 7..0 (key bits 26..19), within bucket B1
    hist[tid] = 0; __syncthreads();
    for (int i = tid; i < n; i += 256)
      if ((int)((sk[i] >> 27) & 0xFF) == B1)
        atomicAdd(&hist[(int)((sk[i] >> 19) & 0xFF)], 1);
    __syncthreads();
    if (tid == 0) {
      int c = 0, b2 = 255;
      for (;; --b2) { c += hist[b2]; if (c >= rem1) break; }
      sB2 = b2; sRem2 = rem1 - (c - hist[b2]);
      sTieCnt = 0;
    }
    __syncthreads();
    int B2 = sB2, rem2 = sRem2;
    int pat = (B1 << 8) | B2;        // m now fully determined; ties differ in idx
    for (int i = tid; i < n; i += 256)
      if ((int)((sk[i] >> 19) & 0xFFFF) == pat) {
        int p = atomicAdd(&sTieCnt, 1);
        if (p < 64) tie[p] = sk[i];
      }
    __syncthreads();
    if (tid == 0) {
      int tc = sTieCnt; if (tc > 64) tc = 64;
      unsigned long long km = 0;
      for (int r = 0; r < rem2; ++r) {     // rem2-th largest (key desc = idx asc)
        int mi = 0; unsigned long long mv = 0;
        for (int i = 0; i < tc; ++i)
          if (tie[i] > mv) { mv = tie[i]; mi = i; }
        km = mv; tie[mi] = 0;
      }
      sKmin = km;
    }
    __syncthreads();
  } else {
    if (tid == 0) sKmin = 1ULL;    // n <= 128: select everything
    __syncthreads();
  }

  unsigned long long kmin = sKmin;
  float acc = 0.0f;
  const float* ob = output + (size_t)b * 125 * HW2;
  const float* rb = regmap + (size_t)b * 100 * HW2;
  for (int i = tid; i < n; i += 256) {
    unsigned long long key = sk[i];
    if (key < kmin) continue;
    int j = (int)(key & 0x7FFFFULL) ^ 0x7FFFF;
    float cls = ob[j];
    if (sign == 0) {
      acc += softplus_f(-cls);               // cm = +1
      int t = j >> 14, s = j & (HW2 - 1);
      #pragma unroll
      for (int c4 = 0; c4 < 4; ++c4) {       // reg channels 25+c*25+t
        float r = ob[(25 + c4 * 25 + t) * HW2 + s];
        float g = rb[(c4 * 25 + t) * HW2 + s];
        float d = r - g, ad = fabsf(d);
        acc += (ad < 1.0f) ? 0.5f * d * d : ad - 0.5f;
      }
    } else {
      acc += softplus_f(cls);                // cm = -1
    }
  }
  red[tid] = acc; __syncthreads();
  for (int st = 128; st > 0; st >>= 1) {
    if (tid < st) red[tid] += red[tid + st];
    __syncthreads();
  }
  if (tid == 0) atomicAdd(out, red[0]);
}

extern "C" void kernel_launch(void* const* d_in, const int* in_sizes, int n_in,
                              void* d_out, int out_size, void* d_ws, size_t ws_size,
                              hipStream_t stream) {
  const float* output    = (const float*)d_in[0];   // (32,125,128,128)
  const float* class_map = (const float*)d_in[1];   // (32,25,128,128)
  const float* regmap    = (const float*)d_in[2];   // (32,100,128,128)
  float* out = (float*)d_out;

  int* cnt = (int*)d_ws;                                           // 64*NSEG ints
  unsigned long long* keys = (unsigned long long*)((char*)d_ws + 64 * NSEG * 4);

  hipMemsetAsync(d_ws, 0, 64 * NSEG * 4, stream);
  hipMemsetAsync(d_out, 0, sizeof(float) * (size_t)out_size, stream);

  dim3 g1(PB / 256, NB);
  k_scan<<<g1, 256, 0, stream>>>(output, class_map, cnt, keys);

  dim3 g2(NB, 2);
  k_select<<<g2, 256, 0, stream>>>(output, regmap, cnt, keys, out);
}

// Round 3
// 468.158 us; speedup vs baseline: 1.9607x; 1.0474x over previous
//
#include <hip/hip_runtime.h>
#include <stdint.h>

#define HW2 16384          // 128*128
#define PB  409600         // 25*HW2, flat per-batch size
#define NB  32
#define MTHRESH 8323072u   // 2^23 - 2^16  -> candidate prob 1/128
#define NSEG 32            // sub-segments per (sign,batch) slot (atomic spreading)
#define SEGCAP 124         // keys per segment (mean ~33, 15 sigma headroom)
#define MAXK (NSEG*SEGCAP) // 3968
#define EPT 4              // elements per thread in k_scan (ILP: 4 threefry chains)

__device__ __forceinline__ uint32_t rotl32(uint32_t x, uint32_t r){ return (x<<r)|(x>>(32u-r)); }

// Exact Threefry-2x32 (20 rounds), matches jax._src.prng.threefry2x32
__device__ __forceinline__ void tf2x32(uint32_t k0,uint32_t k1,uint32_t x0,uint32_t x1,
                                       uint32_t& o0,uint32_t& o1){
  uint32_t k2 = k0 ^ k1 ^ 0x1BD11BDAu;
  x0 += k0; x1 += k1;
#define RND(r) { x0 += x1; x1 = rotl32(x1,(r)); x1 ^= x0; }
  RND(13) RND(15) RND(26) RND(6)
  x0 += k1; x1 += k2 + 1u;
  RND(17) RND(29) RND(16) RND(24)
  x0 += k2; x1 += k0 + 2u;
  RND(13) RND(15) RND(26) RND(6)
  x0 += k0; x1 += k1 + 3u;
  RND(17) RND(29) RND(16) RND(24)
  x0 += k1; x1 += k2 + 4u;
  RND(13) RND(15) RND(26) RND(6)
  x0 += k2; x1 += k0 + 5u;
#undef RND
  o0 = x0; o1 = x1;
}

__device__ __forceinline__ float softplus_f(float x){
  return fmaxf(x, 0.0f) + log1pf(expf(-fabsf(x)));
}

// Pass 1: pr bits for every (b,j). EPT=4 independent interleaved threefry
// chains per thread (R2: one serial ~12cyc/round dep chain capped issue
// efficiency at ~50%). Candidates (top 1/128 by pr) read class_map +
// classification, apply hard-negative mining, append composite key
// (m desc, idx asc via xor) to one of 32 atomic-spread sub-segments.
__global__ void k_scan(const float* __restrict__ output,
                       const float* __restrict__ class_map,
                       int* __restrict__ cnt,                      // 64*NSEG ints
                       unsigned long long* __restrict__ keys)      // 64*NSEG*SEGCAP
{
  int b = blockIdx.y;
  uint32_t kb0, kb1;                 // key_b = threefry((0,42),(0,b)) — SGPR inputs
  tf2x32(0u, 42u, 0u, (uint32_t)b, kb0, kb1);
  uint32_t kb2 = kb0 ^ kb1 ^ 0x1BD11BDAu;

  int jbase = blockIdx.x * (256 * EPT) + threadIdx.x;   // PB = 400 * 1024

  uint32_t x0[EPT], x1[EPT], m4[EPT];
  #pragma unroll
  for (int u = 0; u < EPT; ++u) {
    x0[u] = kb0;
    x1[u] = (uint32_t)(jbase + 256 * u) + kb1;
  }
#define RND4(r) { _Pragma("unroll") for (int u=0;u<EPT;++u){ x0[u]+=x1[u]; x1[u]=rotl32(x1[u],(r)); x1[u]^=x0[u]; } }
#define INJ4(a,bq,i) { _Pragma("unroll") for (int u=0;u<EPT;++u){ x0[u]+=(a); x1[u]+=(bq)+(i); } }
  RND4(13) RND4(15) RND4(26) RND4(6)  INJ4(kb1, kb2, 1u)
  RND4(17) RND4(29) RND4(16) RND4(24) INJ4(kb2, kb0, 2u)
  RND4(13) RND4(15) RND4(26) RND4(6)  INJ4(kb0, kb1, 3u)
  RND4(17) RND4(29) RND4(16) RND4(24) INJ4(kb1, kb2, 4u)
  RND4(13) RND4(15) RND4(26) RND4(6)  INJ4(kb2, kb0, 5u)
#undef RND4
#undef INJ4
  #pragma unroll
  for (int u = 0; u < EPT; ++u) m4[u] = (x0[u] ^ x1[u]) >> 9;  // pr = m * 2^-23

  const float* cmb = class_map + (size_t)b * PB;
  const float* ob  = output    + (size_t)b * 125 * HW2;
  int seg = blockIdx.x & (NSEG - 1);

  #pragma unroll
  for (int u = 0; u < EPT; ++u) {
    uint32_t m = m4[u];
    if (m < MTHRESH) continue;
    int j = jbase + 256 * u;
    float cmv = cmb[j];                  // independent loads issue together
    float cls = ob[j];
    if (cmv == 0.0f) continue;
    float sp = softplus_f(-cmv * cls);
    if (sp < 0.03f) continue;            // mined out (easy example)
    int sign = (cmv > 0.0f) ? 0 : 1;
    int c = (sign * NB + b) * NSEG + seg;
    int n = atomicAdd(&cnt[c], 1);
    if (n < SEGCAP) {
      keys[(size_t)c * SEGCAP + n] =
          (((unsigned long long)m) << 19) | (unsigned long long)(j ^ 0x7FFFF);
    }
  }
}

// Pass 2: per (batch,sign) block: exact top-128 via 2-level 8-bit radix
// select on m (16 varying bits), tie-broken by idx on a tiny tie set, then
// gather losses and reduce. (Verified exact in R2, absmax 0.)
__global__ void k_select(const float* __restrict__ output,
                         const float* __restrict__ regmap,
                         const int* __restrict__ cnt,
                         const unsigned long long* __restrict__ keys,
                         float* __restrict__ out)
{
  __shared__ unsigned long long sk[MAXK];
  __shared__ int scnt[NSEG], sbase[NSEG];
  __shared__ int hist[256];
  __shared__ int sB1, sRem1, sB2, sRem2, sTieCnt, sN;
  __shared__ unsigned long long tie[64];
  __shared__ unsigned long long sKmin;
  __shared__ float red[256];

  int b    = blockIdx.x;    // 0..31
  int sign = blockIdx.y;    // 0 = pos, 1 = neg
  int slot = sign * NB + b;
  int tid  = threadIdx.x;

  if (tid < NSEG) {
    int c = cnt[slot * NSEG + tid];
    scnt[tid] = c > SEGCAP ? SEGCAP : c;
  }
  __syncthreads();
  if (tid == 0) {
    int s = 0;
    for (int i = 0; i < NSEG; ++i) { sbase[i] = s; s += scnt[i]; }
    sN = s;
  }
  __syncthreads();
  int n = sN;
  for (int u = tid; u < NSEG * SEGCAP; u += 256) {
    int seg = u / SEGCAP, i = u - seg * SEGCAP;
    if (i < scnt[seg])
      sk[sbase[seg] + i] = keys[(size_t)(slot * NSEG + seg) * SEGCAP + i];
  }
  __syncthreads();

  if (n > 128) {
    // level 1: m bits 15..8 (key bits 34..27)
    hist[tid] = 0; __syncthreads();
    for (int i = tid; i < n; i += 256)
      atomicAdd(&hist[(int)((sk[i] >> 27) & 0xFF)], 1);
    __syncthreads();
    if (tid == 0) {
      int c = 0, b1 = 255;
      for (;; --b1) { c += hist[b1]; if (c >= 128) break; }
      sB1 = b1; sRem1 = 128 - (c - hist[b1]);
    }
    __syncthreads();
    int B1 = sB1, rem1 = sRem1;
    // level 2: m bits 7..0 (key bits 26..19), within bucket B1
    hist[tid] = 0; __syncthreads();
    for (int i = tid; i < n; i += 256)
      if ((int)((sk[i] >> 27) & 0xFF) == B1)
        atomicAdd(&hist[(int)((sk[i] >> 19) & 0xFF)], 1);
    __syncthreads();
    if (tid == 0) {
      int c = 0, b2 = 255;
      for (;; --b2) { c += hist[b2]; if (c >= rem1) break; }
      sB2 = b2; sRem2 = rem1 - (c - hist[b2]);
      sTieCnt = 0;
    }
    __syncthreads();
    int B2 = sB2, rem2 = sRem2;
    int pat = (B1 << 8) | B2;        // m fully determined; ties differ in idx
    for (int i = tid; i < n; i += 256)
      if ((int)((sk[i] >> 19) & 0xFFFF) == pat) {
        int p = atomicAdd(&sTieCnt, 1);
        if (p < 64) tie[p] = sk[i];
      }
    __syncthreads();
    if (tid == 0) {
      int tc = sTieCnt; if (tc > 64) tc = 64;
      unsigned long long km = 0;
      for (int r = 0; r < rem2; ++r) {     // rem2-th largest (key desc = idx asc)
        int mi = 0; unsigned long long mv = 0;
        for (int i = 0; i < tc; ++i)
          if (tie[i] > mv) { mv = tie[i]; mi = i; }
        km = mv; tie[mi] = 0;
      }
      sKmin = km;
    }
    __syncthreads();
  } else {
    if (tid == 0) sKmin = 1ULL;    // n <= 128: select everything
    __syncthreads();
  }

  unsigned long long kmin = sKmin;
  float acc = 0.0f;
  const float* ob = output + (size_t)b * 125 * HW2;
  const float* rb = regmap + (size_t)b * 100 * HW2;
  for (int i = tid; i < n; i += 256) {
    unsigned long long key = sk[i];
    if (key < kmin) continue;
    int j = (int)(key & 0x7FFFFULL) ^ 0x7FFFF;
    float cls = ob[j];
    if (sign == 0) {
      acc += softplus_f(-cls);               // cm = +1
      int t = j >> 14, s = j & (HW2 - 1);
      #pragma unroll
      for (int c4 = 0; c4 < 4; ++c4) {       // reg channels 25+c*25+t
        float r = ob[(25 + c4 * 25 + t) * HW2 + s];
        float g = rb[(c4 * 25 + t) * HW2 + s];
        float d = r - g, ad = fabsf(d);
        acc += (ad < 1.0f) ? 0.5f * d * d : ad - 0.5f;
      }
    } else {
      acc += softplus_f(cls);                // cm = -1
    }
  }
  red[tid] = acc; __syncthreads();
  for (int st = 128; st > 0; st >>= 1) {
    if (tid < st) red[tid] += red[tid + st];
    __syncthreads();
  }
  if (tid == 0) atomicAdd(out, red[0]);
}

extern "C" void kernel_launch(void* const* d_in, const int* in_sizes, int n_in,
                              void* d_out, int out_size, void* d_ws, size_t ws_size,
                              hipStream_t stream) {
  const float* output    = (const float*)d_in[0];   // (32,125,128,128)
  const float* class_map = (const float*)d_in[1];   // (32,25,128,128)
  const float* regmap    = (const float*)d_in[2];   // (32,100,128,128)
  float* out = (float*)d_out;

  int* cnt = (int*)d_ws;                                           // 64*NSEG ints
  unsigned long long* keys = (unsigned long long*)((char*)d_ws + 64 * NSEG * 4);

  hipMemsetAsync(d_ws, 0, 64 * NSEG * 4, stream);
  hipMemsetAsync(d_out, 0, sizeof(float) * (size_t)out_size, stream);

  dim3 g1(PB / (256 * EPT), NB);   // (400, 32)
  k_scan<<<g1, 256, 0, stream>>>(output, class_map, cnt, keys);

  dim3 g2(NB, 2);
  k_select<<<g2, 256, 0, stream>>>(output, regmap, cnt, keys, out);
}